// Round 1
// baseline (691.588 us; speedup 1.0000x reference)
//
#include <hip/hip_runtime.h>

// ---------------- problem constants ----------------
#define HID   2048
#define NHEAD 16
#define HD    128
#define SEQ   2048
#define BATCH 2
#define MROWS (BATCH*SEQ)        // 4096
#define NQKV  (3*HID)            // 6144
#define INV_NORM 0.08838834764831845f
#define LOG2E    1.4426950408889634f

typedef __attribute__((ext_vector_type(8))) __bf16 bf16x8;
typedef __attribute__((ext_vector_type(4))) float  f32x4;

typedef __attribute__((address_space(1))) void GV;
typedef __attribute__((address_space(3))) void LV;

__device__ __forceinline__ void async16(const void* g, void* l) {
  __builtin_amdgcn_global_load_lds((const GV*)g, (LV*)l, 16, 0, 0);
}

__device__ __forceinline__ unsigned short f2bf(float f) {
  unsigned u = __builtin_bit_cast(unsigned, f);
  u += 0x7FFFu + ((u >> 16) & 1u);       // RNE
  return (unsigned short)(u >> 16);
}

__device__ __forceinline__ void mfma16(f32x4& c, bf16x8 a, bf16x8 b) {
  c = __builtin_amdgcn_mfma_f32_16x16x32_bf16(a, b, c, 0, 0, 0);
}

// ---------------- fp32 -> bf16 cast ----------------
__global__ __launch_bounds__(256) void cvt_kernel(const float* __restrict__ src,
                                                  unsigned short* __restrict__ dst, int n) {
  int i = (blockIdx.x * 256 + threadIdx.x) * 4;
  if (i >= n) return;
  float4 v = *(const float4*)(src + i);
  ushort4 o;
  o.x = f2bf(v.x); o.y = f2bf(v.y); o.z = f2bf(v.z); o.w = f2bf(v.w);
  *(ushort4*)(dst + i) = o;
}

// ---------------- 128x128 NT GEMM core (m97 structure) ----------------
// C[M][N] = A[M][K] * B[N][K]^T ; K multiple of 32, tiles 128x128.
__device__ __forceinline__ void gemm_core(const unsigned short* __restrict__ A,
                                          const unsigned short* __restrict__ Bm,
                                          int K, int m0, int n0,
                                          unsigned short* As, unsigned short* Bs,
                                          f32x4 (&acc)[4][4]) {
  const int tid  = threadIdx.x;
  const int w    = tid >> 6;
  const int lane = tid & 63;
  const int l16  = lane & 15;
  const int quad = lane >> 4;
  const int wm   = (w & 1) * 64;
  const int wn   = (w >> 1) * 64;

  const f32x4 zero = {0.f, 0.f, 0.f, 0.f};
#pragma unroll
  for (int i = 0; i < 4; ++i)
#pragma unroll
    for (int j = 0; j < 4; ++j) acc[i][j] = zero;

  for (int k0 = 0; k0 < K; k0 += 32) {
    __syncthreads();   // previous tile's compute done
#pragma unroll
    for (int is = 0; is < 2; ++is) {
      int c = is * 256 + w * 64 + lane;               // 16B chunk id, 0..511
      const unsigned short* ga = A  + (size_t)(m0 + (c >> 2)) * K + k0 + (c & 3) * 8;
      async16(ga, (char*)As + is * 4096 + w * 1024);  // wave-uniform LDS base
      const unsigned short* gb = Bm + (size_t)(n0 + (c >> 2)) * K + k0 + (c & 3) * 8;
      async16(gb, (char*)Bs + is * 4096 + w * 1024);
    }
    __syncthreads();   // drains vmcnt(0) -> tiles visible

    bf16x8 af[4], bfp[4];
#pragma unroll
    for (int i = 0; i < 4; ++i)
      af[i] = *(const bf16x8*)(As + (wm + i * 16 + l16) * 32 + quad * 8);
#pragma unroll
    for (int j = 0; j < 4; ++j)
      bfp[j] = *(const bf16x8*)(Bs + (wn + j * 16 + l16) * 32 + quad * 8);
#pragma unroll
    for (int i = 0; i < 4; ++i)
#pragma unroll
      for (int j = 0; j < 4; ++j) mfma16(acc[i][j], af[i], bfp[j]);
  }
}

// ---------------- GEMM 1: QKV projection, bf16 out + bias ----------------
__global__ __launch_bounds__(256) void gemm_qkv_kernel(
    const unsigned short* __restrict__ Xb, const unsigned short* __restrict__ Wb,
    const float* __restrict__ bq, const float* __restrict__ bk,
    const float* __restrict__ bv, unsigned short* __restrict__ Cout) {
  __shared__ __align__(16) unsigned short As[128 * 32];
  __shared__ __align__(16) unsigned short Bs[128 * 32];
  f32x4 acc[4][4];
  const int m0 = blockIdx.y * 128, n0 = blockIdx.x * 128;
  gemm_core(Xb, Wb, HID, m0, n0, As, Bs, acc);

  const int tid = threadIdx.x, w = tid >> 6, lane = tid & 63;
  const int l16 = lane & 15, quad = lane >> 4;
  const int wm = (w & 1) * 64, wn = (w >> 1) * 64;
#pragma unroll
  for (int j = 0; j < 4; ++j) {
    int ng = n0 + wn + j * 16 + l16;
    float bias = (ng < HID) ? bq[ng] : (ng < 2 * HID ? bk[ng - HID] : bv[ng - 2 * HID]);
#pragma unroll
    for (int i = 0; i < 4; ++i)
#pragma unroll
      for (int r = 0; r < 4; ++r) {
        int mg = m0 + wm + i * 16 + quad * 4 + r;      // C/D: row=quad*4+r, col=l16
        Cout[(size_t)mg * NQKV + ng] = f2bf(acc[i][j][r] + bias);
      }
  }
}

// ---------------- GEMM 2: out-proj + bias + residual, fp32 out ----------------
__global__ __launch_bounds__(256) void gemm_out_kernel(
    const unsigned short* __restrict__ Ctx, const unsigned short* __restrict__ Wdb,
    const float* __restrict__ bd, const float* __restrict__ Res,
    float* __restrict__ Out) {
  __shared__ __align__(16) unsigned short As[128 * 32];
  __shared__ __align__(16) unsigned short Bs[128 * 32];
  f32x4 acc[4][4];
  const int m0 = blockIdx.y * 128, n0 = blockIdx.x * 128;
  gemm_core(Ctx, Wdb, HID, m0, n0, As, Bs, acc);

  const int tid = threadIdx.x, w = tid >> 6, lane = tid & 63;
  const int l16 = lane & 15, quad = lane >> 4;
  const int wm = (w & 1) * 64, wn = (w >> 1) * 64;
#pragma unroll
  for (int j = 0; j < 4; ++j) {
    int ng = n0 + wn + j * 16 + l16;
    float bias = bd[ng];
#pragma unroll
    for (int i = 0; i < 4; ++i)
#pragma unroll
      for (int r = 0; r < 4; ++r) {
        int mg = m0 + wm + i * 16 + quad * 4 + r;
        size_t off = (size_t)mg * HID + ng;
        Out[off] = acc[i][j][r] + bias + Res[off];
      }
  }
}

// ---------------- flash attention ----------------
// grid = (SEQ/64, BATCH*NHEAD); block = 256 (4 waves, each owns 16 q-rows)
// Vts swizzle: element V[s][d] lives at d*72 + ((s + 8*((d>>3)&7)) & 63)
__device__ __forceinline__ int vt_idx(int d, int s) {
  return d * 72 + ((s + 8 * ((d >> 3) & 7)) & 63);
}

__global__ __launch_bounds__(256) void attn_kernel(
    const unsigned short* __restrict__ QKV, const float* __restrict__ alibi,
    unsigned short* __restrict__ Ctx) {
  __shared__ __align__(16) unsigned short Qs[64 * 136];   // [q][d], pad 8
  __shared__ __align__(16) unsigned short Ks[64 * 136];   // [k][d], pad 8
  __shared__ __align__(16) unsigned short Vts[128 * 72];  // [d][s], swizzled
  __shared__ __align__(16) unsigned short Ps[64 * 72];    // [q][k], pad 8

  const int tid = threadIdx.x, wq = tid >> 6, lane = tid & 63;
  const int l16 = lane & 15, quad = lane >> 4;
  const int q0 = blockIdx.x * 64;
  const int bh = blockIdx.y, b = bh >> 4, h = bh & 15;
  const size_t rowbase = (size_t)b * SEQ;
  const float* ali = alibi + (size_t)bh * SEQ;

  // stage Q tile (64 x 128)
  for (int c = tid; c < 1024; c += 256) {
    int r = c >> 4, seg = c & 15;
    const unsigned short* g = QKV + (rowbase + q0 + r) * NQKV + h * HD + seg * 8;
    *(uint4*)(Qs + r * 136 + seg * 8) = *(const uint4*)g;
  }

  float m_r[4], l_r[4];
  f32x4 oacc[8];
  const f32x4 zero = {0.f, 0.f, 0.f, 0.f};
#pragma unroll
  for (int n = 0; n < 8; ++n) oacc[n] = zero;
#pragma unroll
  for (int r = 0; r < 4; ++r) { m_r[r] = -3.0e38f; l_r[r] = 0.f; }

  for (int kt = 0; kt < SEQ / 64; ++kt) {
    __syncthreads();   // prior PV reads done before K/V overwrite
    // stage K tile
    for (int c = tid; c < 1024; c += 256) {
      int r = c >> 4, seg = c & 15;
      const unsigned short* g = QKV + (rowbase + kt * 64 + r) * NQKV + HID + h * HD + seg * 8;
      *(uint4*)(Ks + r * 136 + seg * 8) = *(const uint4*)g;
    }
    // stage V tile, transposed + swizzled
    for (int c = tid; c < 1024; c += 256) {
      int r = c >> 4, seg = c & 15;
      const unsigned short* g = QKV + (rowbase + kt * 64 + r) * NQKV + 2 * HID + h * HD + seg * 8;
      uint4 t = *(const uint4*)g;
      const unsigned short* e = (const unsigned short*)&t;
#pragma unroll
      for (int x = 0; x < 8; ++x) Vts[vt_idx(seg * 8 + x, r)] = e[x];
    }
    __syncthreads();

    // S = Q K^T  (per wave: 16 q-rows x 64 keys)
    f32x4 sacc[4];
#pragma unroll
    for (int j = 0; j < 4; ++j) sacc[j] = zero;
#pragma unroll
    for (int ks = 0; ks < 4; ++ks) {
      bf16x8 aq = *(const bf16x8*)(Qs + (wq * 16 + l16) * 136 + ks * 32 + quad * 8);
#pragma unroll
      for (int j = 0; j < 4; ++j) {
        bf16x8 bk = *(const bf16x8*)(Ks + (j * 16 + l16) * 136 + ks * 32 + quad * 8);
        mfma16(sacc[j], aq, bk);
      }
    }

    // scale + alibi ; online softmax (row = quad*4 + r, col = j*16 + l16)
    float sv[4][4];
#pragma unroll
    for (int j = 0; j < 4; ++j) {
      float aj = ali[kt * 64 + j * 16 + l16];
#pragma unroll
      for (int r = 0; r < 4; ++r) sv[j][r] = sacc[j][r] * INV_NORM + aj;
    }
    float mnew[4], alpha[4], rsum[4];
#pragma unroll
    for (int r = 0; r < 4; ++r) {
      float v = fmaxf(fmaxf(sv[0][r], sv[1][r]), fmaxf(sv[2][r], sv[3][r]));
#pragma unroll
      for (int off = 8; off >= 1; off >>= 1) v = fmaxf(v, __shfl_xor(v, off, 64));
      mnew[r] = fmaxf(m_r[r], v);
      alpha[r] = exp2f((m_r[r] - mnew[r]) * LOG2E);
      rsum[r] = 0.f;
    }
#pragma unroll
    for (int j = 0; j < 4; ++j)
#pragma unroll
      for (int r = 0; r < 4; ++r) {
        float p = exp2f((sv[j][r] - mnew[r]) * LOG2E);
        Ps[(wq * 16 + quad * 4 + r) * 72 + j * 16 + l16] = f2bf(p);
        rsum[r] += p;
      }
#pragma unroll
    for (int r = 0; r < 4; ++r) {
      float v = rsum[r];
#pragma unroll
      for (int off = 8; off >= 1; off >>= 1) v += __shfl_xor(v, off, 64);
      l_r[r] = l_r[r] * alpha[r] + v;
      m_r[r] = mnew[r];
    }
#pragma unroll
    for (int n = 0; n < 8; ++n)
#pragma unroll
      for (int r = 0; r < 4; ++r) oacc[n][r] *= alpha[r];

    __syncthreads();   // Ps visible (and ordered) before PV

    // O += P V   (per wave: 16 q-rows x 128 d)
#pragma unroll
    for (int ks = 0; ks < 2; ++ks) {
      bf16x8 ap = *(const bf16x8*)(Ps + (wq * 16 + l16) * 72 + ks * 32 + quad * 8);
#pragma unroll
      for (int n = 0; n < 8; ++n) {
        bf16x8 bv = *(const bf16x8*)(Vts + vt_idx(n * 16 + l16, ks * 32 + quad * 8));
        mfma16(oacc[n], ap, bv);
      }
    }
  }

  // epilogue: O /= l ; write ctx (bf16) in [B,S,H] layout
#pragma unroll
  for (int n = 0; n < 8; ++n)
#pragma unroll
    for (int r = 0; r < 4; ++r) {
      float o = oacc[n][r] / l_r[r];
      size_t row = rowbase + q0 + wq * 16 + quad * 4 + r;
      Ctx[row * HID + h * HD + n * 16 + l16] = f2bf(o);
    }
}

// ---------------- launch ----------------
extern "C" void kernel_launch(void* const* d_in, const int* in_sizes, int n_in,
                              void* d_out, int out_size, void* d_ws, size_t ws_size,
                              hipStream_t stream) {
  const float* hidden   = (const float*)d_in[0];
  const float* residual = (const float*)d_in[1];
  const float* alibi    = (const float*)d_in[2];
  const float* Wq = (const float*)d_in[3];
  const float* bq = (const float*)d_in[4];
  const float* Wk = (const float*)d_in[5];
  const float* bk = (const float*)d_in[6];
  const float* Wv = (const float*)d_in[7];
  const float* bv = (const float*)d_in[8];
  const float* Wd = (const float*)d_in[9];
  const float* bd = (const float*)d_in[10];
  float* out = (float*)d_out;

  unsigned short* Xb    = (unsigned short*)d_ws;                    // 4096*2048
  unsigned short* Wqkvb = Xb + (size_t)MROWS * HID;                 // 6144*2048
  unsigned short* Wdb   = Wqkvb + (size_t)NQKV * HID;               // 2048*2048
  unsigned short* QKVb  = Wdb + (size_t)HID * HID;                  // 4096*6144
  unsigned short* Ctxb  = QKVb + (size_t)MROWS * NQKV;              // 4096*2048

  const int nX = MROWS * HID, nW = HID * HID;
  cvt_kernel<<<nX / 4 / 256, 256, 0, stream>>>(hidden, Xb, nX);
  cvt_kernel<<<nW / 4 / 256, 256, 0, stream>>>(Wq, Wqkvb, nW);
  cvt_kernel<<<nW / 4 / 256, 256, 0, stream>>>(Wk, Wqkvb + (size_t)HID * HID, nW);
  cvt_kernel<<<nW / 4 / 256, 256, 0, stream>>>(Wv, Wqkvb + (size_t)2 * HID * HID, nW);
  cvt_kernel<<<nW / 4 / 256, 256, 0, stream>>>(Wd, Wdb, nW);

  gemm_qkv_kernel<<<dim3(NQKV / 128, MROWS / 128), 256, 0, stream>>>(Xb, Wqkvb, bq, bk, bv, QKVb);
  attn_kernel<<<dim3(SEQ / 64, BATCH * NHEAD), 256, 0, stream>>>(QKVb, alibi, Ctxb);
  gemm_out_kernel<<<dim3(HID / 128, MROWS / 128), 256, 0, stream>>>(Ctxb, Wdb, bd, residual, out);
}

// Round 2
// 516.618 us; speedup vs baseline: 1.3387x; 1.3387x over previous
//
#include <hip/hip_runtime.h>

// ---------------- problem constants ----------------
#define HID   2048
#define NHEAD 16
#define HD    128
#define SEQ   2048
#define BATCH 2
#define MROWS (BATCH*SEQ)        // 4096
#define NQKV  (3*HID)            // 6144
#define INV_NORM 0.08838834764831845f
#define LOG2E    1.4426950408889634f
#define SCALE_L2 (INV_NORM*LOG2E)

typedef __attribute__((ext_vector_type(8))) __bf16 bf16x8;
typedef __attribute__((ext_vector_type(4))) float  f32x4;

typedef __attribute__((address_space(1))) void GV;
typedef __attribute__((address_space(3))) void LV;

__device__ __forceinline__ void async16(const void* g, void* l) {
  __builtin_amdgcn_global_load_lds((const GV*)g, (LV*)l, 16, 0, 0);
}

__device__ __forceinline__ unsigned short f2bf(float f) {
  unsigned u = __builtin_bit_cast(unsigned, f);
  u += 0x7FFFu + ((u >> 16) & 1u);       // RNE
  return (unsigned short)(u >> 16);
}

__device__ __forceinline__ void mfma16(f32x4& c, bf16x8 a, bf16x8 b) {
  c = __builtin_amdgcn_mfma_f32_16x16x32_bf16(a, b, c, 0, 0, 0);
}

// ---------------- fp32 -> bf16 cast ----------------
__global__ __launch_bounds__(256) void cvt_kernel(const float* __restrict__ src,
                                                  unsigned short* __restrict__ dst, int n) {
  int i = (blockIdx.x * 256 + threadIdx.x) * 4;
  if (i >= n) return;
  float4 v = *(const float4*)(src + i);
  ushort4 o;
  o.x = f2bf(v.x); o.y = f2bf(v.y); o.z = f2bf(v.z); o.w = f2bf(v.w);
  *(ushort4*)(dst + i) = o;
}

// ---------------- 128x128 NT GEMM core (m97 structure) ----------------
__device__ __forceinline__ void gemm_core(const unsigned short* __restrict__ A,
                                          const unsigned short* __restrict__ Bm,
                                          int K, int m0, int n0,
                                          unsigned short* As, unsigned short* Bs,
                                          f32x4 (&acc)[4][4]) {
  const int tid  = threadIdx.x;
  const int w    = tid >> 6;
  const int lane = tid & 63;
  const int l16  = lane & 15;
  const int quad = lane >> 4;
  const int wm   = (w & 1) * 64;
  const int wn   = (w >> 1) * 64;

  const f32x4 zero = {0.f, 0.f, 0.f, 0.f};
#pragma unroll
  for (int i = 0; i < 4; ++i)
#pragma unroll
    for (int j = 0; j < 4; ++j) acc[i][j] = zero;

  for (int k0 = 0; k0 < K; k0 += 32) {
    __syncthreads();
#pragma unroll
    for (int is = 0; is < 2; ++is) {
      int c = is * 256 + w * 64 + lane;
      const unsigned short* ga = A  + (size_t)(m0 + (c >> 2)) * K + k0 + (c & 3) * 8;
      async16(ga, (char*)As + is * 4096 + w * 1024);
      const unsigned short* gb = Bm + (size_t)(n0 + (c >> 2)) * K + k0 + (c & 3) * 8;
      async16(gb, (char*)Bs + is * 4096 + w * 1024);
    }
    __syncthreads();

    bf16x8 af[4], bfp[4];
#pragma unroll
    for (int i = 0; i < 4; ++i)
      af[i] = *(const bf16x8*)(As + (wm + i * 16 + l16) * 32 + quad * 8);
#pragma unroll
    for (int j = 0; j < 4; ++j)
      bfp[j] = *(const bf16x8*)(Bs + (wn + j * 16 + l16) * 32 + quad * 8);
#pragma unroll
    for (int i = 0; i < 4; ++i)
#pragma unroll
      for (int j = 0; j < 4; ++j) mfma16(acc[i][j], af[i], bfp[j]);
  }
}

// ---------------- GEMM 1: QKV projection, bf16 out + bias ----------------
__global__ __launch_bounds__(256) void gemm_qkv_kernel(
    const unsigned short* __restrict__ Xb, const unsigned short* __restrict__ Wb,
    const float* __restrict__ bq, const float* __restrict__ bk,
    const float* __restrict__ bv, unsigned short* __restrict__ Cout) {
  __shared__ __align__(16) unsigned short As[128 * 32];
  __shared__ __align__(16) unsigned short Bs[128 * 32];
  f32x4 acc[4][4];
  const int m0 = blockIdx.y * 128, n0 = blockIdx.x * 128;
  gemm_core(Xb, Wb, HID, m0, n0, As, Bs, acc);

  const int tid = threadIdx.x, w = tid >> 6, lane = tid & 63;
  const int l16 = lane & 15, quad = lane >> 4;
  const int wm = (w & 1) * 64, wn = (w >> 1) * 64;
#pragma unroll
  for (int j = 0; j < 4; ++j) {
    int ng = n0 + wn + j * 16 + l16;
    float bias = (ng < HID) ? bq[ng] : (ng < 2 * HID ? bk[ng - HID] : bv[ng - 2 * HID]);
#pragma unroll
    for (int i = 0; i < 4; ++i)
#pragma unroll
      for (int r = 0; r < 4; ++r) {
        int mg = m0 + wm + i * 16 + quad * 4 + r;
        Cout[(size_t)mg * NQKV + ng] = f2bf(acc[i][j][r] + bias);
      }
  }
}

// ---------------- GEMM 2: out-proj + bias + residual, fp32 out ----------------
__global__ __launch_bounds__(256) void gemm_out_kernel(
    const unsigned short* __restrict__ Ctx, const unsigned short* __restrict__ Wdb,
    const float* __restrict__ bd, const float* __restrict__ Res,
    float* __restrict__ Out) {
  __shared__ __align__(16) unsigned short As[128 * 32];
  __shared__ __align__(16) unsigned short Bs[128 * 32];
  f32x4 acc[4][4];
  const int m0 = blockIdx.y * 128, n0 = blockIdx.x * 128;
  gemm_core(Ctx, Wdb, HID, m0, n0, As, Bs, acc);

  const int tid = threadIdx.x, w = tid >> 6, lane = tid & 63;
  const int l16 = lane & 15, quad = lane >> 4;
  const int wm = (w & 1) * 64, wn = (w >> 1) * 64;
#pragma unroll
  for (int j = 0; j < 4; ++j) {
    int ng = n0 + wn + j * 16 + l16;
    float bias = bd[ng];
#pragma unroll
    for (int i = 0; i < 4; ++i)
#pragma unroll
      for (int r = 0; r < 4; ++r) {
        int mg = m0 + wm + i * 16 + quad * 4 + r;
        size_t off = (size_t)mg * HID + ng;
        Out[off] = acc[i][j][r] + bias + Res[off];
      }
  }
}

// ---------------- V transpose: QKV V-part -> Vt[bh][d][s] ----------------
// grid (SEQ/64, HD/64, BH=32), block 256
__global__ __launch_bounds__(256) void vtrans_kernel(const unsigned short* __restrict__ QKV,
                                                     unsigned short* __restrict__ Vt) {
  __shared__ __align__(16) unsigned short T[64][72];
  const int s0 = blockIdx.x * 64, d0 = blockIdx.y * 64, bh = blockIdx.z;
  const int b = bh >> 4, h = bh & 15;
  const int tid = threadIdx.x;
  // read 64 s-rows x 64 d (128 B per row = 8 chunks); 512 chunks over 256 threads
#pragma unroll
  for (int i = 0; i < 2; ++i) {
    int idx = i * 256 + tid;
    int r = idx >> 3, ch = idx & 7;
    const unsigned short* g = QKV + ((size_t)b * SEQ + s0 + r) * NQKV + 2 * HID + h * HD + d0 + ch * 8;
    *(uint4*)(&T[r][ch * 8]) = *(const uint4*)g;
  }
  __syncthreads();
  // write 64 d-rows x 64 s; gather columns from T
#pragma unroll
  for (int i = 0; i < 2; ++i) {
    int idx = i * 256 + tid;
    int d = idx >> 3, ch = idx & 7;
    unsigned short v[8];
#pragma unroll
    for (int x = 0; x < 8; ++x) v[x] = T[ch * 8 + x][d];
    unsigned short* g = Vt + ((size_t)bh * HD + d0 + d) * SEQ + s0 + ch * 8;
    *(uint4*)g = *(const uint4*)v;
  }
}

// ---------------- flash attention (fixed-max softmax) ----------------
// grid = (SEQ/64, BATCH*NHEAD); block 256 (4 waves, each 16 q-rows)
// Qs/Ks: [64 rows][16 chunks of 16B], slot = r*16 + (g ^ (r&15))
// Vts:   [128 rows][8 chunks of 16B], slot = r*8  + (g ^ (r&7))
__global__ __launch_bounds__(256) void attn_kernel(
    const unsigned short* __restrict__ QKV, const unsigned short* __restrict__ Vt,
    const float* __restrict__ alibi, unsigned short* __restrict__ Ctx) {
  __shared__ __align__(16) unsigned short Qs[64 * 128];
  __shared__ __align__(16) unsigned short Ks[64 * 128];
  __shared__ __align__(16) unsigned short Vts[128 * 64];
  __shared__ __align__(16) unsigned short Ps[64 * 72];

  const int tid = threadIdx.x, w = tid >> 6, lane = tid & 63;
  const int l16 = lane & 15, quad = lane >> 4;
  const int q0 = blockIdx.x * 64;
  const int bh = blockIdx.y, b = bh >> 4, h = bh & 15;
  const size_t rowbase = (size_t)b * SEQ;
  const float* ali = alibi + (size_t)bh * SEQ;
  const unsigned short* Vbh = Vt + (size_t)bh * HD * SEQ;

  // stage Q (swizzled async16)
  {
    const unsigned short* qbase = QKV + (rowbase + q0) * NQKV + h * HD;
#pragma unroll
    for (int i = 0; i < 4; ++i) {
      int slot = i * 256 + w * 64 + lane;
      int r = slot >> 4, g = (slot & 15) ^ (r & 15);
      async16(qbase + (size_t)r * NQKV + g * 8, (char*)Qs + (i * 256 + w * 64) * 16);
    }
  }

  f32x4 oacc[8];
  float l_acc[4];
  const f32x4 zero = {0.f, 0.f, 0.f, 0.f};
#pragma unroll
  for (int n = 0; n < 8; ++n) oacc[n] = zero;
#pragma unroll
  for (int r = 0; r < 4; ++r) l_acc[r] = 0.f;

  for (int kt = 0; kt < SEQ / 64; ++kt) {
    __syncthreads();   // prior tile's LDS reads done
    {
      const unsigned short* kbase = QKV + (rowbase + kt * 64) * NQKV + HID + h * HD;
#pragma unroll
      for (int i = 0; i < 4; ++i) {
        int slot = i * 256 + w * 64 + lane;
        int r = slot >> 4, g = (slot & 15) ^ (r & 15);
        async16(kbase + (size_t)r * NQKV + g * 8, (char*)Ks + (i * 256 + w * 64) * 16);
      }
      const unsigned short* vbase = Vbh + kt * 64;
#pragma unroll
      for (int i = 0; i < 4; ++i) {
        int slot = i * 256 + w * 64 + lane;
        int r = slot >> 3, g = (slot & 7) ^ (r & 7);
        async16(vbase + (size_t)r * SEQ + g * 8, (char*)Vts + (i * 256 + w * 64) * 16);
      }
    }
    __syncthreads();   // drain vmcnt -> tiles visible

    // S = Q K^T (16 q-rows x 64 keys per wave)
    f32x4 sacc[4];
#pragma unroll
    for (int j = 0; j < 4; ++j) sacc[j] = zero;
#pragma unroll
    for (int ks = 0; ks < 4; ++ks) {
      int xr = (ks * 4 + quad) ^ l16;
      bf16x8 aq = *(const bf16x8*)(Qs + ((w * 16 + l16) * 16 + xr) * 8);
#pragma unroll
      for (int j = 0; j < 4; ++j) {
        bf16x8 bk = *(const bf16x8*)(Ks + ((j * 16 + l16) * 16 + xr) * 8);
        mfma16(sacc[j], aq, bk);
      }
    }

    // fixed-max softmax: p = exp2(s*inv_norm*log2e + alibi*log2e)
    const float* alik = ali + kt * 64;
#pragma unroll
    for (int j = 0; j < 4; ++j) {
      float aj2 = alik[j * 16 + l16] * LOG2E;
#pragma unroll
      for (int r = 0; r < 4; ++r) {
        float p = __builtin_amdgcn_exp2f(sacc[j][r] * SCALE_L2 + aj2);
        Ps[(w * 16 + quad * 4 + r) * 72 + j * 16 + l16] = f2bf(p);
        l_acc[r] += p;
      }
    }
    // Ps is wave-private (rows w*16..w*16+15): no barrier needed

    // O += P V
#pragma unroll
    for (int ks = 0; ks < 2; ++ks) {
      bf16x8 ap = *(const bf16x8*)(Ps + (w * 16 + l16) * 72 + ks * 32 + quad * 8);
#pragma unroll
      for (int n = 0; n < 8; ++n) {
        int xr = (ks * 4 + quad) ^ (l16 & 7);
        bf16x8 bv = *(const bf16x8*)(Vts + ((n * 16 + l16) * 8 + xr) * 8);
        mfma16(oacc[n], ap, bv);
      }
    }
  }

  // reduce denominator across the 16 l16 lanes (once)
  float inv[4];
#pragma unroll
  for (int r = 0; r < 4; ++r) {
    float v = l_acc[r];
#pragma unroll
    for (int off = 1; off <= 8; off <<= 1) v += __shfl_xor(v, off, 64);
    inv[r] = 1.0f / v;
  }

#pragma unroll
  for (int n = 0; n < 8; ++n)
#pragma unroll
    for (int r = 0; r < 4; ++r) {
      size_t row = rowbase + q0 + w * 16 + quad * 4 + r;
      Ctx[row * HID + h * HD + n * 16 + l16] = f2bf(oacc[n][r] * inv[r]);
    }
}

// ---------------- launch ----------------
extern "C" void kernel_launch(void* const* d_in, const int* in_sizes, int n_in,
                              void* d_out, int out_size, void* d_ws, size_t ws_size,
                              hipStream_t stream) {
  const float* hidden   = (const float*)d_in[0];
  const float* residual = (const float*)d_in[1];
  const float* alibi    = (const float*)d_in[2];
  const float* Wq = (const float*)d_in[3];
  const float* bq = (const float*)d_in[4];
  const float* Wk = (const float*)d_in[5];
  const float* bk = (const float*)d_in[6];
  const float* Wv = (const float*)d_in[7];
  const float* bv = (const float*)d_in[8];
  const float* Wd = (const float*)d_in[9];
  const float* bd = (const float*)d_in[10];
  float* out = (float*)d_out;

  unsigned short* Xb    = (unsigned short*)d_ws;                    // 4096*2048
  unsigned short* Wqkvb = Xb + (size_t)MROWS * HID;                 // 6144*2048
  unsigned short* Wdb   = Wqkvb + (size_t)NQKV * HID;               // 2048*2048
  unsigned short* QKVb  = Wdb + (size_t)HID * HID;                  // 4096*6144
  unsigned short* Ctxb  = QKVb + (size_t)MROWS * NQKV;              // 4096*2048
  // Vt (32*128*2048 shorts = 16.8 MB) reuses Wqkvb region (dead after gemm_qkv)
  unsigned short* Vtb   = Wqkvb;

  const int nX = MROWS * HID, nW = HID * HID;
  cvt_kernel<<<nX / 4 / 256, 256, 0, stream>>>(hidden, Xb, nX);
  cvt_kernel<<<nW / 4 / 256, 256, 0, stream>>>(Wq, Wqkvb, nW);
  cvt_kernel<<<nW / 4 / 256, 256, 0, stream>>>(Wk, Wqkvb + (size_t)HID * HID, nW);
  cvt_kernel<<<nW / 4 / 256, 256, 0, stream>>>(Wv, Wqkvb + (size_t)2 * HID * HID, nW);
  cvt_kernel<<<nW / 4 / 256, 256, 0, stream>>>(Wd, Wdb, nW);

  gemm_qkv_kernel<<<dim3(NQKV / 128, MROWS / 128), 256, 0, stream>>>(Xb, Wqkvb, bq, bk, bv, QKVb);
  vtrans_kernel<<<dim3(SEQ / 64, HD / 64, BATCH * NHEAD), 256, 0, stream>>>(QKVb, Vtb);
  attn_kernel<<<dim3(SEQ / 64, BATCH * NHEAD), 256, 0, stream>>>(QKVb, Vtb, alibi, Ctxb);
  gemm_out_kernel<<<dim3(HID / 128, MROWS / 128), 256, 0, stream>>>(Ctxb, Wdb, bd, residual, out);
}

// Round 3
// 488.704 us; speedup vs baseline: 1.4151x; 1.0571x over previous
//
#include <hip/hip_runtime.h>

// ---------------- problem constants ----------------
#define HID   2048
#define NHEAD 16
#define HD    128
#define SEQ   2048
#define BATCH 2
#define MROWS (BATCH*SEQ)        // 4096
#define NQKV  (3*HID)            // 6144
#define INV_NORM 0.08838834764831845f
#define LOG2E    1.4426950408889634f
#define SCALE_L2 (INV_NORM*LOG2E)

typedef __attribute__((ext_vector_type(8))) __bf16 bf16x8;
typedef __attribute__((ext_vector_type(4))) float  f32x4;

typedef __attribute__((address_space(1))) void GV;
typedef __attribute__((address_space(3))) void LV;

__device__ __forceinline__ void async16(const void* g, void* l) {
  __builtin_amdgcn_global_load_lds((const GV*)g, (LV*)l, 16, 0, 0);
}

__device__ __forceinline__ unsigned short f2bf(float f) {
  unsigned u = __builtin_bit_cast(unsigned, f);
  u += 0x7FFFu + ((u >> 16) & 1u);       // RNE
  return (unsigned short)(u >> 16);
}

__device__ __forceinline__ void mfma16(f32x4& c, bf16x8 a, bf16x8 b) {
  c = __builtin_amdgcn_mfma_f32_16x16x32_bf16(a, b, c, 0, 0, 0);
}

// ---------------- fp32 -> bf16 casts ----------------
__global__ __launch_bounds__(256) void cvt_kernel(const float* __restrict__ src,
                                                  unsigned short* __restrict__ dst, int n) {
  int i = (blockIdx.x * 256 + threadIdx.x) * 4;
  if (i >= n) return;
  float4 v = *(const float4*)(src + i);
  ushort4 o;
  o.x = f2bf(v.x); o.y = f2bf(v.y); o.z = f2bf(v.z); o.w = f2bf(v.w);
  *(ushort4*)(dst + i) = o;
}

// 4 weight matrices (Wq,Wk,Wv,Wd) -> contiguous bf16 region; grid.y selects matrix
__global__ __launch_bounds__(256) void cvtw_kernel(const float* __restrict__ W0,
                                                   const float* __restrict__ W1,
                                                   const float* __restrict__ W2,
                                                   const float* __restrict__ W3,
                                                   unsigned short* __restrict__ dst) {
  int sel = blockIdx.y;
  const float* src = (sel == 0) ? W0 : (sel == 1) ? W1 : (sel == 2) ? W2 : W3;
  unsigned short* d = dst + (size_t)sel * HID * HID;
  int i = (blockIdx.x * 256 + threadIdx.x) * 4;
  float4 v = *(const float4*)(src + i);
  ushort4 o;
  o.x = f2bf(v.x); o.y = f2bf(v.y); o.z = f2bf(v.z); o.w = f2bf(v.w);
  *(ushort4*)(d + i) = o;
}

// ---------------- 128x128 NT GEMM core, BK=64, XOR-swizzled LDS ----------------
// C[M][N] = A[M][K] * B[N][K]^T ; K multiple of 64, tiles 128x128.
// LDS tile [128 rows][8 chunks of 16B]; chunk c of row r stored at slot r*8 + (c^(r&7)).
__device__ __forceinline__ void gemm_core(const unsigned short* __restrict__ A,
                                          const unsigned short* __restrict__ Bm,
                                          int K, int m0, int n0,
                                          unsigned short* As, unsigned short* Bs,
                                          f32x4 (&acc)[4][4]) {
  const int tid  = threadIdx.x;
  const int w    = tid >> 6;
  const int lane = tid & 63;
  const int l16  = lane & 15;
  const int quad = lane >> 4;
  const int wm   = (w & 1) * 64;
  const int wn   = (w >> 1) * 64;

  const f32x4 zero = {0.f, 0.f, 0.f, 0.f};
#pragma unroll
  for (int i = 0; i < 4; ++i)
#pragma unroll
    for (int j = 0; j < 4; ++j) acc[i][j] = zero;

  for (int k0 = 0; k0 < K; k0 += 64) {
    __syncthreads();   // previous tile's LDS reads done
#pragma unroll
    for (int i = 0; i < 4; ++i) {
      int slot = i * 256 + w * 64 + lane;              // 0..1023
      int r = slot >> 3;
      int c = (slot & 7) ^ (r & 7);                    // source-chunk permutation
      async16(A  + (size_t)(m0 + r) * K + k0 + c * 8, (char*)As + (size_t)(i * 256 + w * 64) * 16);
      async16(Bm + (size_t)(n0 + r) * K + k0 + c * 8, (char*)Bs + (size_t)(i * 256 + w * 64) * 16);
    }
    __syncthreads();   // drain vmcnt -> tiles visible

#pragma unroll
    for (int kk = 0; kk < 2; ++kk) {
      bf16x8 af[4], bfp[4];
#pragma unroll
      for (int i = 0; i < 4; ++i) {
        int rr = wm + i * 16 + l16;
        af[i] = *(const bf16x8*)(As + ((rr * 8 + (((kk * 4 + quad)) ^ (rr & 7))) * 8));
      }
#pragma unroll
      for (int j = 0; j < 4; ++j) {
        int rr = wn + j * 16 + l16;
        bfp[j] = *(const bf16x8*)(Bs + ((rr * 8 + (((kk * 4 + quad)) ^ (rr & 7))) * 8));
      }
#pragma unroll
      for (int i = 0; i < 4; ++i)
#pragma unroll
        for (int j = 0; j < 4; ++j) mfma16(acc[i][j], af[i], bfp[j]);
    }
  }
}

// ---------------- GEMM 1: QKV projection, bf16 out + bias ----------------
__global__ __launch_bounds__(256) void gemm_qkv_kernel(
    const unsigned short* __restrict__ Xb, const unsigned short* __restrict__ Wb,
    const float* __restrict__ bq, const float* __restrict__ bk,
    const float* __restrict__ bv, unsigned short* __restrict__ Cout) {
  __shared__ __align__(16) unsigned short As[128 * 64];
  __shared__ __align__(16) unsigned short Bs[128 * 64];
  f32x4 acc[4][4];
  const int m0 = blockIdx.y * 128, n0 = blockIdx.x * 128;
  gemm_core(Xb, Wb, HID, m0, n0, As, Bs, acc);

  const int tid = threadIdx.x, w = tid >> 6, lane = tid & 63;
  const int l16 = lane & 15, quad = lane >> 4;
  const int wm = (w & 1) * 64, wn = (w >> 1) * 64;
#pragma unroll
  for (int j = 0; j < 4; ++j) {
    int ng = n0 + wn + j * 16 + l16;
    float bias = (ng < HID) ? bq[ng] : (ng < 2 * HID ? bk[ng - HID] : bv[ng - 2 * HID]);
#pragma unroll
    for (int i = 0; i < 4; ++i)
#pragma unroll
      for (int r = 0; r < 4; ++r) {
        int mg = m0 + wm + i * 16 + quad * 4 + r;      // C/D: row=quad*4+r, col=l16
        Cout[(size_t)mg * NQKV + ng] = f2bf(acc[i][j][r] + bias);
      }
  }
}

// ---------------- GEMM 2: out-proj + bias + residual, fp32 out ----------------
__global__ __launch_bounds__(256) void gemm_out_kernel(
    const unsigned short* __restrict__ Ctx, const unsigned short* __restrict__ Wdb,
    const float* __restrict__ bd, const float* __restrict__ Res,
    float* __restrict__ Out) {
  __shared__ __align__(16) unsigned short As[128 * 64];
  __shared__ __align__(16) unsigned short Bs[128 * 64];
  f32x4 acc[4][4];
  const int m0 = blockIdx.y * 128, n0 = blockIdx.x * 128;
  gemm_core(Ctx, Wdb, HID, m0, n0, As, Bs, acc);

  const int tid = threadIdx.x, w = tid >> 6, lane = tid & 63;
  const int l16 = lane & 15, quad = lane >> 4;
  const int wm = (w & 1) * 64, wn = (w >> 1) * 64;
#pragma unroll
  for (int j = 0; j < 4; ++j) {
    int ng = n0 + wn + j * 16 + l16;
    float bias = bd[ng];
#pragma unroll
    for (int i = 0; i < 4; ++i)
#pragma unroll
      for (int r = 0; r < 4; ++r) {
        int mg = m0 + wm + i * 16 + quad * 4 + r;
        size_t off = (size_t)mg * HID + ng;
        Out[off] = acc[i][j][r] + bias + Res[off];
      }
  }
}

// ---------------- V transpose: QKV V-part -> Vt[bh][d][s] ----------------
__global__ __launch_bounds__(256) void vtrans_kernel(const unsigned short* __restrict__ QKV,
                                                     unsigned short* __restrict__ Vt) {
  __shared__ __align__(16) unsigned short T[64][72];
  const int s0 = blockIdx.x * 64, d0 = blockIdx.y * 64, bh = blockIdx.z;
  const int b = bh >> 4, h = bh & 15;
  const int tid = threadIdx.x;
#pragma unroll
  for (int i = 0; i < 2; ++i) {
    int idx = i * 256 + tid;
    int r = idx >> 3, ch = idx & 7;
    const unsigned short* g = QKV + ((size_t)b * SEQ + s0 + r) * NQKV + 2 * HID + h * HD + d0 + ch * 8;
    *(uint4*)(&T[r][ch * 8]) = *(const uint4*)g;
  }
  __syncthreads();
#pragma unroll
  for (int i = 0; i < 2; ++i) {
    int idx = i * 256 + tid;
    int d = idx >> 3, ch = idx & 7;
    unsigned short v[8];
#pragma unroll
    for (int x = 0; x < 8; ++x) v[x] = T[ch * 8 + x][d];
    unsigned short* g = Vt + ((size_t)bh * HD + d0 + d) * SEQ + s0 + ch * 8;
    *(uint4*)g = *(const uint4*)v;
  }
}

// ---------------- flash attention (fixed-max softmax) ----------------
// grid = (SEQ/64, BATCH*NHEAD); block 256 (4 waves, each 16 q-rows)
__global__ __launch_bounds__(256) void attn_kernel(
    const unsigned short* __restrict__ QKV, const unsigned short* __restrict__ Vt,
    const float* __restrict__ alibi, unsigned short* __restrict__ Ctx) {
  __shared__ __align__(16) unsigned short Qs[64 * 128];
  __shared__ __align__(16) unsigned short Ks[64 * 128];
  __shared__ __align__(16) unsigned short Vts[128 * 64];
  __shared__ __align__(16) unsigned short Ps[64 * 72];

  const int tid = threadIdx.x, w = tid >> 6, lane = tid & 63;
  const int l16 = lane & 15, quad = lane >> 4;
  const int q0 = blockIdx.x * 64;
  const int bh = blockIdx.y, b = bh >> 4, h = bh & 15;
  const size_t rowbase = (size_t)b * SEQ;
  const float* ali = alibi + (size_t)bh * SEQ;
  const unsigned short* Vbh = Vt + (size_t)bh * HD * SEQ;

  {
    const unsigned short* qbase = QKV + (rowbase + q0) * NQKV + h * HD;
#pragma unroll
    for (int i = 0; i < 4; ++i) {
      int slot = i * 256 + w * 64 + lane;
      int r = slot >> 4, g = (slot & 15) ^ (r & 15);
      async16(qbase + (size_t)r * NQKV + g * 8, (char*)Qs + (i * 256 + w * 64) * 16);
    }
  }

  f32x4 oacc[8];
  float l_acc[4];
  const f32x4 zero = {0.f, 0.f, 0.f, 0.f};
#pragma unroll
  for (int n = 0; n < 8; ++n) oacc[n] = zero;
#pragma unroll
  for (int r = 0; r < 4; ++r) l_acc[r] = 0.f;

  for (int kt = 0; kt < SEQ / 64; ++kt) {
    __syncthreads();
    {
      const unsigned short* kbase = QKV + (rowbase + kt * 64) * NQKV + HID + h * HD;
#pragma unroll
      for (int i = 0; i < 4; ++i) {
        int slot = i * 256 + w * 64 + lane;
        int r = slot >> 4, g = (slot & 15) ^ (r & 15);
        async16(kbase + (size_t)r * NQKV + g * 8, (char*)Ks + (i * 256 + w * 64) * 16);
      }
      const unsigned short* vbase = Vbh + kt * 64;
#pragma unroll
      for (int i = 0; i < 4; ++i) {
        int slot = i * 256 + w * 64 + lane;
        int r = slot >> 3, g = (slot & 7) ^ (r & 7);
        async16(vbase + (size_t)r * SEQ + g * 8, (char*)Vts + (i * 256 + w * 64) * 16);
      }
    }
    __syncthreads();

    f32x4 sacc[4];
#pragma unroll
    for (int j = 0; j < 4; ++j) sacc[j] = zero;
#pragma unroll
    for (int ks = 0; ks < 4; ++ks) {
      int xr = (ks * 4 + quad) ^ l16;
      bf16x8 aq = *(const bf16x8*)(Qs + ((w * 16 + l16) * 16 + xr) * 8);
#pragma unroll
      for (int j = 0; j < 4; ++j) {
        bf16x8 bk = *(const bf16x8*)(Ks + ((j * 16 + l16) * 16 + xr) * 8);
        mfma16(sacc[j], aq, bk);
      }
    }

    const float* alik = ali + kt * 64;
#pragma unroll
    for (int j = 0; j < 4; ++j) {
      float aj2 = alik[j * 16 + l16] * LOG2E;
#pragma unroll
      for (int r = 0; r < 4; ++r) {
        float p = __builtin_amdgcn_exp2f(sacc[j][r] * SCALE_L2 + aj2);
        Ps[(w * 16 + quad * 4 + r) * 72 + j * 16 + l16] = f2bf(p);
        l_acc[r] += p;
      }
    }

#pragma unroll
    for (int ks = 0; ks < 2; ++ks) {
      bf16x8 ap = *(const bf16x8*)(Ps + (w * 16 + l16) * 72 + ks * 32 + quad * 8);
#pragma unroll
      for (int n = 0; n < 8; ++n) {
        int xr = (ks * 4 + quad) ^ (l16 & 7);
        bf16x8 bv = *(const bf16x8*)(Vts + ((n * 16 + l16) * 8 + xr) * 8);
        mfma16(oacc[n], ap, bv);
      }
    }
  }

  float inv[4];
#pragma unroll
  for (int r = 0; r < 4; ++r) {
    float v = l_acc[r];
#pragma unroll
    for (int off = 1; off <= 8; off <<= 1) v += __shfl_xor(v, off, 64);
    inv[r] = 1.0f / v;
  }

#pragma unroll
  for (int n = 0; n < 8; ++n)
#pragma unroll
    for (int r = 0; r < 4; ++r) {
      size_t row = rowbase + q0 + w * 16 + quad * 4 + r;
      Ctx[row * HID + h * HD + n * 16 + l16] = f2bf(oacc[n][r] * inv[r]);
    }
}

// ---------------- launch ----------------
extern "C" void kernel_launch(void* const* d_in, const int* in_sizes, int n_in,
                              void* d_out, int out_size, void* d_ws, size_t ws_size,
                              hipStream_t stream) {
  const float* hidden   = (const float*)d_in[0];
  const float* residual = (const float*)d_in[1];
  const float* alibi    = (const float*)d_in[2];
  const float* Wq = (const float*)d_in[3];
  const float* bq = (const float*)d_in[4];
  const float* Wk = (const float*)d_in[5];
  const float* bk = (const float*)d_in[6];
  const float* Wv = (const float*)d_in[7];
  const float* bv = (const float*)d_in[8];
  const float* Wd = (const float*)d_in[9];
  const float* bd = (const float*)d_in[10];
  float* out = (float*)d_out;

  unsigned short* Xb    = (unsigned short*)d_ws;                    // 4096*2048
  unsigned short* Wqkvb = Xb + (size_t)MROWS * HID;                 // 6144*2048
  unsigned short* Wdb   = Wqkvb + (size_t)NQKV * HID;               // 2048*2048 (contiguous after Wqkvb)
  unsigned short* QKVb  = Wdb + (size_t)HID * HID;                  // 4096*6144
  unsigned short* Ctxb  = QKVb + (size_t)MROWS * NQKV;              // 4096*2048
  unsigned short* Vtb   = Wqkvb;  // Vt (16.8 MB) reuses Wqkvb region (dead after gemm_qkv)

  const int nX = MROWS * HID, nW = HID * HID;
  cvt_kernel<<<nX / 4 / 256, 256, 0, stream>>>(hidden, Xb, nX);
  cvtw_kernel<<<dim3(nW / 4 / 256, 4), 256, 0, stream>>>(Wq, Wk, Wv, Wd, Wqkvb);

  gemm_qkv_kernel<<<dim3(NQKV / 128, MROWS / 128), 256, 0, stream>>>(Xb, Wqkvb, bq, bk, bv, QKVb);
  vtrans_kernel<<<dim3(SEQ / 64, HD / 64, BATCH * NHEAD), 256, 0, stream>>>(QKVb, Vtb);
  attn_kernel<<<dim3(SEQ / 64, BATCH * NHEAD), 256, 0, stream>>>(QKVb, Vtb, alibi, Ctxb);
  gemm_out_kernel<<<dim3(HID / 128, MROWS / 128), 256, 0, stream>>>(Ctxb, Wdb, bd, residual, out);
}

// Round 4
// 440.854 us; speedup vs baseline: 1.5687x; 1.1085x over previous
//
#include <hip/hip_runtime.h>

// ---------------- problem constants ----------------
#define HID   2048
#define NHEAD 16
#define HD    128
#define SEQ   2048
#define BATCH 2
#define MROWS (BATCH*SEQ)        // 4096
#define NQKV  (3*HID)            // 6144
#define INV_NORM 0.08838834764831845f
#define LOG2E    1.4426950408889634f
#define SCALE_L2 (INV_NORM*LOG2E)

typedef __attribute__((ext_vector_type(8)))  __bf16 bf16x8;
typedef __attribute__((ext_vector_type(4)))  float  f32x4;
typedef __attribute__((ext_vector_type(16))) float  f32x16;

typedef __attribute__((address_space(1))) void GV;
typedef __attribute__((address_space(3))) void LV;

__device__ __forceinline__ void async16(const void* g, void* l) {
  __builtin_amdgcn_global_load_lds((const GV*)g, (LV*)l, 16, 0, 0);
}

__device__ __forceinline__ unsigned short f2bf(float f) {
  unsigned u = __builtin_bit_cast(unsigned, f);
  u += 0x7FFFu + ((u >> 16) & 1u);       // RNE
  return (unsigned short)(u >> 16);
}

__device__ __forceinline__ unsigned pkbf(float a, float b) {
#if __has_builtin(__builtin_amdgcn_cvt_pk_bf16_f32)
  typedef __attribute__((ext_vector_type(2))) __bf16 bf16x2;
  bf16x2 r = __builtin_amdgcn_cvt_pk_bf16_f32(a, b);
  return __builtin_bit_cast(unsigned, r);
#else
  return (unsigned)f2bf(a) | ((unsigned)f2bf(b) << 16);
#endif
}

__device__ __forceinline__ void mfma16(f32x4& c, bf16x8 a, bf16x8 b) {
  c = __builtin_amdgcn_mfma_f32_16x16x32_bf16(a, b, c, 0, 0, 0);
}

// ---------------- fp32 -> bf16 casts ----------------
__global__ __launch_bounds__(256) void cvt_kernel(const float* __restrict__ src,
                                                  unsigned short* __restrict__ dst, int n) {
  int i = (blockIdx.x * 256 + threadIdx.x) * 4;
  if (i >= n) return;
  float4 v = *(const float4*)(src + i);
  ushort4 o;
  o.x = f2bf(v.x); o.y = f2bf(v.y); o.z = f2bf(v.z); o.w = f2bf(v.w);
  *(ushort4*)(dst + i) = o;
}

__global__ __launch_bounds__(256) void cvtw_kernel(const float* __restrict__ W0,
                                                   const float* __restrict__ W1,
                                                   const float* __restrict__ W2,
                                                   const float* __restrict__ W3,
                                                   unsigned short* __restrict__ dst) {
  int sel = blockIdx.y;
  const float* src = (sel == 0) ? W0 : (sel == 1) ? W1 : (sel == 2) ? W2 : W3;
  unsigned short* d = dst + (size_t)sel * HID * HID;
  int i = (blockIdx.x * 256 + threadIdx.x) * 4;
  float4 v = *(const float4*)(src + i);
  ushort4 o;
  o.x = f2bf(v.x); o.y = f2bf(v.y); o.z = f2bf(v.z); o.w = f2bf(v.w);
  *(ushort4*)(d + i) = o;
}

// ---------------- 128x128 NT GEMM core, BK=64, XOR-swizzled LDS ----------------
__device__ __forceinline__ void gemm_core(const unsigned short* __restrict__ A,
                                          const unsigned short* __restrict__ Bm,
                                          int K, int m0, int n0,
                                          unsigned short* As, unsigned short* Bs,
                                          f32x4 (&acc)[4][4]) {
  const int tid  = threadIdx.x;
  const int w    = tid >> 6;
  const int lane = tid & 63;
  const int l16  = lane & 15;
  const int quad = lane >> 4;
  const int wm   = (w & 1) * 64;
  const int wn   = (w >> 1) * 64;

  const f32x4 zero = {0.f, 0.f, 0.f, 0.f};
#pragma unroll
  for (int i = 0; i < 4; ++i)
#pragma unroll
    for (int j = 0; j < 4; ++j) acc[i][j] = zero;

  for (int k0 = 0; k0 < K; k0 += 64) {
    __syncthreads();
#pragma unroll
    for (int i = 0; i < 4; ++i) {
      int slot = i * 256 + w * 64 + lane;
      int r = slot >> 3;
      int c = (slot & 7) ^ (r & 7);
      async16(A  + (size_t)(m0 + r) * K + k0 + c * 8, (char*)As + (size_t)(i * 256 + w * 64) * 16);
      async16(Bm + (size_t)(n0 + r) * K + k0 + c * 8, (char*)Bs + (size_t)(i * 256 + w * 64) * 16);
    }
    __syncthreads();

#pragma unroll
    for (int kk = 0; kk < 2; ++kk) {
      bf16x8 af[4], bfp[4];
#pragma unroll
      for (int i = 0; i < 4; ++i) {
        int rr = wm + i * 16 + l16;
        af[i] = *(const bf16x8*)(As + ((rr * 8 + (((kk * 4 + quad)) ^ (rr & 7))) * 8));
      }
#pragma unroll
      for (int j = 0; j < 4; ++j) {
        int rr = wn + j * 16 + l16;
        bfp[j] = *(const bf16x8*)(Bs + ((rr * 8 + (((kk * 4 + quad)) ^ (rr & 7))) * 8));
      }
#pragma unroll
      for (int i = 0; i < 4; ++i)
#pragma unroll
        for (int j = 0; j < 4; ++j) mfma16(acc[i][j], af[i], bfp[j]);
    }
  }
}

// ---------------- GEMM 1: QKV projection, bf16 out + bias ----------------
__global__ __launch_bounds__(256) void gemm_qkv_kernel(
    const unsigned short* __restrict__ Xb, const unsigned short* __restrict__ Wb,
    const float* __restrict__ bq, const float* __restrict__ bk,
    const float* __restrict__ bv, unsigned short* __restrict__ Cout) {
  __shared__ __align__(16) unsigned short As[128 * 64];
  __shared__ __align__(16) unsigned short Bs[128 * 64];
  f32x4 acc[4][4];
  const int m0 = blockIdx.y * 128, n0 = blockIdx.x * 128;
  gemm_core(Xb, Wb, HID, m0, n0, As, Bs, acc);

  const int tid = threadIdx.x, w = tid >> 6, lane = tid & 63;
  const int l16 = lane & 15, quad = lane >> 4;
  const int wm = (w & 1) * 64, wn = (w >> 1) * 64;
#pragma unroll
  for (int j = 0; j < 4; ++j) {
    int ng = n0 + wn + j * 16 + l16;
    float bias = (ng < HID) ? bq[ng] : (ng < 2 * HID ? bk[ng - HID] : bv[ng - 2 * HID]);
#pragma unroll
    for (int i = 0; i < 4; ++i)
#pragma unroll
      for (int r = 0; r < 4; ++r) {
        int mg = m0 + wm + i * 16 + quad * 4 + r;
        Cout[(size_t)mg * NQKV + ng] = f2bf(acc[i][j][r] + bias);
      }
  }
}

// ---------------- GEMM 2: out-proj + bias + residual, fp32 out ----------------
__global__ __launch_bounds__(256) void gemm_out_kernel(
    const unsigned short* __restrict__ Ctx, const unsigned short* __restrict__ Wdb,
    const float* __restrict__ bd, const float* __restrict__ Res,
    float* __restrict__ Out) {
  __shared__ __align__(16) unsigned short As[128 * 64];
  __shared__ __align__(16) unsigned short Bs[128 * 64];
  f32x4 acc[4][4];
  const int m0 = blockIdx.y * 128, n0 = blockIdx.x * 128;
  gemm_core(Ctx, Wdb, HID, m0, n0, As, Bs, acc);

  const int tid = threadIdx.x, w = tid >> 6, lane = tid & 63;
  const int l16 = lane & 15, quad = lane >> 4;
  const int wm = (w & 1) * 64, wn = (w >> 1) * 64;
#pragma unroll
  for (int j = 0; j < 4; ++j) {
    int ng = n0 + wn + j * 16 + l16;
    float bias = bd[ng];
#pragma unroll
    for (int i = 0; i < 4; ++i)
#pragma unroll
      for (int r = 0; r < 4; ++r) {
        int mg = m0 + wm + i * 16 + quad * 4 + r;
        size_t off = (size_t)mg * HID + ng;
        Out[off] = acc[i][j][r] + bias + Res[off];
      }
  }
}

// ---------------- V transpose: QKV V-part -> Vt[bh][d][s] ----------------
__global__ __launch_bounds__(256) void vtrans_kernel(const unsigned short* __restrict__ QKV,
                                                     unsigned short* __restrict__ Vt) {
  __shared__ __align__(16) unsigned short T[64][72];
  const int s0 = blockIdx.x * 64, d0 = blockIdx.y * 64, bh = blockIdx.z;
  const int b = bh >> 4, h = bh & 15;
  const int tid = threadIdx.x;
#pragma unroll
  for (int i = 0; i < 2; ++i) {
    int idx = i * 256 + tid;
    int r = idx >> 3, ch = idx & 7;
    const unsigned short* g = QKV + ((size_t)b * SEQ + s0 + r) * NQKV + 2 * HID + h * HD + d0 + ch * 8;
    *(uint4*)(&T[r][ch * 8]) = *(const uint4*)g;
  }
  __syncthreads();
#pragma unroll
  for (int i = 0; i < 2; ++i) {
    int idx = i * 256 + tid;
    int d = idx >> 3, ch = idx & 7;
    unsigned short v[8];
#pragma unroll
    for (int x = 0; x < 8; ++x) v[x] = T[ch * 8 + x][d];
    unsigned short* g = Vt + ((size_t)bh * HD + d0 + d) * SEQ + s0 + ch * 8;
    *(uint4*)g = *(const uint4*)v;
  }
}

// ---------------- flash attention, 32x32 MFMA, S^T trick ----------------
// grid = (SEQ/128, BATCH*NHEAD); block 256 (4 waves, each 32 q-rows)
// LDS: Ks [64 k-rows][16 chunks, c^(r&15)] 16KB; Vts [128 d-rows][8 chunks, c^(r&7)] 16KB;
//      Ps [128 q][72] 18KB.  Q staged once in Ks∪Vts alias, hoisted to regs.
__global__ __launch_bounds__(256, 2) void attn_kernel(
    const unsigned short* __restrict__ QKV, const unsigned short* __restrict__ Vt,
    const float* __restrict__ alibi, unsigned short* __restrict__ Ctx) {
  __shared__ __align__(16) char smem[51200];
  unsigned short* Ks  = (unsigned short*)smem;
  unsigned short* Vts = (unsigned short*)(smem + 16384);
  unsigned short* Ps  = (unsigned short*)(smem + 32768);
  unsigned short* Qs  = (unsigned short*)smem;          // alias: Q staging (32 KB)

  const int tid = threadIdx.x, w = tid >> 6, lane = tid & 63;
  const int l32 = lane & 31, h = lane >> 5;
  const int q0 = blockIdx.x * 128;
  const int bh = blockIdx.y, b = bh >> 4, hh = bh & 15;
  const size_t rowbase = (size_t)b * SEQ;
  const float* ali = alibi + (size_t)bh * SEQ;
  const unsigned short* Vbh = Vt + (size_t)bh * HD * SEQ;

  // ---- stage Q tile (128 x 128) once; hoist fragments to registers ----
  {
    const unsigned short* qbase = QKV + (rowbase + q0) * NQKV + hh * HD;
#pragma unroll
    for (int i = 0; i < 8; ++i) {
      int slot = i * 256 + w * 64 + lane;              // 0..2047
      int r = slot >> 4, c = (slot & 15) ^ (r & 15);
      async16(qbase + (size_t)r * NQKV + c * 8, (char*)Qs + (size_t)(i * 256 + w * 64) * 16);
    }
  }
  __syncthreads();
  bf16x8 qf[8];
  {
    int qr = w * 32 + l32;
#pragma unroll
    for (int ks = 0; ks < 8; ++ks) {
      int c = (ks * 2 + h) ^ (qr & 15);
      qf[ks] = *(const bf16x8*)(Qs + (qr * 16 + c) * 8);
    }
  }

  f32x16 oacc[4];
  float l_acc = 0.f;
#pragma unroll
  for (int nb = 0; nb < 4; ++nb)
#pragma unroll
    for (int r = 0; r < 16; ++r) oacc[nb][r] = 0.f;

  __syncthreads();   // qf reads complete before K staging overwrites alias

  for (int kt = 0; kt < SEQ / 64; ++kt) {
    // stage K (64x128) and Vt (128x64) tiles
    {
      const unsigned short* kbase = QKV + (rowbase + kt * 64) * NQKV + HID + hh * HD;
#pragma unroll
      for (int i = 0; i < 4; ++i) {
        int slot = i * 256 + w * 64 + lane;
        int r = slot >> 4, c = (slot & 15) ^ (r & 15);
        async16(kbase + (size_t)r * NQKV + c * 8, (char*)Ks + (size_t)(i * 256 + w * 64) * 16);
      }
      const unsigned short* vbase = Vbh + kt * 64;
#pragma unroll
      for (int i = 0; i < 4; ++i) {
        int slot = i * 256 + w * 64 + lane;
        int r = slot >> 3, c = (slot & 7) ^ (r & 7);
        async16(vbase + (size_t)r * SEQ + c * 8, (char*)Vts + (size_t)(i * 256 + w * 64) * 16);
      }
    }
    __syncthreads();   // drain vmcnt -> tiles visible

    // S^T = K Q^T : D[m=key 64][n=q 32], K-depth 128
    f32x16 sacc[2];
#pragma unroll
    for (int mb = 0; mb < 2; ++mb)
#pragma unroll
      for (int r = 0; r < 16; ++r) sacc[mb][r] = 0.f;
#pragma unroll
    for (int ks = 0; ks < 8; ++ks) {
      int c = (ks * 2 + h) ^ (l32 & 15);
#pragma unroll
      for (int mb = 0; mb < 2; ++mb) {
        bf16x8 kf = *(const bf16x8*)(Ks + ((mb * 32 + l32) * 16 + ((ks * 2 + h) ^ (l32 & 15))) * 8);
        sacc[mb] = __builtin_amdgcn_mfma_f32_32x32x16_bf16(kf, qf[ks], sacc[mb], 0, 0, 0);
      }
      (void)c;
    }

    // softmax (fixed-max): p = exp2(s*scale + a*log2e); per-lane q = l32+32w
    const float* alik = ali + kt * 64 + 4 * h;
    const int qrow = w * 32 + l32;
#pragma unroll
    for (int mb = 0; mb < 2; ++mb) {
#pragma unroll
      for (int g = 0; g < 4; ++g) {
        float4 av = *(const float4*)(alik + mb * 32 + g * 8);
        float p0 = __builtin_amdgcn_exp2f(sacc[mb][g * 4 + 0] * SCALE_L2 + av.x * LOG2E);
        float p1 = __builtin_amdgcn_exp2f(sacc[mb][g * 4 + 1] * SCALE_L2 + av.y * LOG2E);
        float p2 = __builtin_amdgcn_exp2f(sacc[mb][g * 4 + 2] * SCALE_L2 + av.z * LOG2E);
        float p3 = __builtin_amdgcn_exp2f(sacc[mb][g * 4 + 3] * SCALE_L2 + av.w * LOG2E);
        l_acc += (p0 + p1) + (p2 + p3);
        uint2 pk;
        pk.x = pkbf(p0, p1);
        pk.y = pkbf(p2, p3);
        *(uint2*)(Ps + qrow * 72 + mb * 32 + g * 8 + 4 * h) = pk;
      }
    }
    // Ps rows are wave-private: no barrier needed before PV

    // O += P V : D[m=q 32][n=d 128], K-depth 64
#pragma unroll
    for (int ks2 = 0; ks2 < 4; ++ks2) {
      bf16x8 pf = *(const bf16x8*)(Ps + qrow * 72 + ks2 * 16 + h * 8);
#pragma unroll
      for (int nb = 0; nb < 4; ++nb) {
        bf16x8 vf = *(const bf16x8*)(Vts + ((nb * 32 + l32) * 8 + ((ks2 * 2 + h) ^ (l32 & 7))) * 8);
        oacc[nb] = __builtin_amdgcn_mfma_f32_32x32x16_bf16(pf, vf, oacc[nb], 0, 0, 0);
      }
    }
    __syncthreads();   // PV reads done before next staging overwrite
  }

  // denominator: combine h-halves, then gather per C/D-row
  float lf = l_acc + __shfl_xor(l_acc, 32, 64);
  float rinv[16];
#pragma unroll
  for (int reg = 0; reg < 16; ++reg) {
    int row = (reg & 3) + 8 * (reg >> 2) + 4 * h;
    rinv[reg] = 1.0f / __shfl(lf, row, 64);
  }

#pragma unroll
  for (int nb = 0; nb < 4; ++nb)
#pragma unroll
    for (int reg = 0; reg < 16; ++reg) {
      int row = (reg & 3) + 8 * (reg >> 2) + 4 * h;
      size_t qg = rowbase + q0 + w * 32 + row;
      Ctx[qg * HID + hh * HD + nb * 32 + l32] = f2bf(oacc[nb][reg] * rinv[reg]);
    }
}

// ---------------- launch ----------------
extern "C" void kernel_launch(void* const* d_in, const int* in_sizes, int n_in,
                              void* d_out, int out_size, void* d_ws, size_t ws_size,
                              hipStream_t stream) {
  const float* hidden   = (const float*)d_in[0];
  const float* residual = (const float*)d_in[1];
  const float* alibi    = (const float*)d_in[2];
  const float* Wq = (const float*)d_in[3];
  const float* bq = (const float*)d_in[4];
  const float* Wk = (const float*)d_in[5];
  const float* bk = (const float*)d_in[6];
  const float* Wv = (const float*)d_in[7];
  const float* bv = (const float*)d_in[8];
  const float* Wd = (const float*)d_in[9];
  const float* bd = (const float*)d_in[10];
  float* out = (float*)d_out;

  unsigned short* Xb    = (unsigned short*)d_ws;                    // 4096*2048
  unsigned short* Wqkvb = Xb + (size_t)MROWS * HID;                 // 6144*2048
  unsigned short* Wdb   = Wqkvb + (size_t)NQKV * HID;               // 2048*2048
  unsigned short* QKVb  = Wdb + (size_t)HID * HID;                  // 4096*6144
  unsigned short* Ctxb  = QKVb + (size_t)MROWS * NQKV;              // 4096*2048
  unsigned short* Vtb   = Wqkvb;  // Vt reuses Wqkvb region (dead after gemm_qkv)

  const int nX = MROWS * HID, nW = HID * HID;
  cvt_kernel<<<nX / 4 / 256, 256, 0, stream>>>(hidden, Xb, nX);
  cvtw_kernel<<<dim3(nW / 4 / 256, 4), 256, 0, stream>>>(Wq, Wk, Wv, Wd, Wqkvb);

  gemm_qkv_kernel<<<dim3(NQKV / 128, MROWS / 128), 256, 0, stream>>>(Xb, Wqkvb, bq, bk, bv, QKVb);
  vtrans_kernel<<<dim3(SEQ / 64, HD / 64, BATCH * NHEAD), 256, 0, stream>>>(QKVb, Vtb);
  attn_kernel<<<dim3(SEQ / 128, BATCH * NHEAD), 256, 0, stream>>>(QKVb, Vtb, alibi, Ctxb);
  gemm_out_kernel<<<dim3(HID / 128, MROWS / 128), 256, 0, stream>>>(Ctxb, Wdb, bd, residual, out);
}